// Round 11
// baseline (22.896 us; speedup 1.0000x reference)
//
#include <hip/hip_runtime.h>

#define K_SAMP 256
#define D_HID 64
#define SCALER_FE 7.0f

typedef _Float16 half8  __attribute__((ext_vector_type(8)));
typedef __fp16   fp16x2 __attribute__((ext_vector_type(2)));
typedef float    f32x4  __attribute__((ext_vector_type(4)));

union H8P { fp16x2 h2[4]; half8 h8; };

__device__ __forceinline__ half8 h8zero() {
    half8 a;
    #pragma unroll
    for (int j = 0; j < 8; ++j) a[j] = (_Float16)0.f;
    return a;
}

// DPP add: x += (x shifted by row_shr:N); shifted-out lanes contribute 0.
// row = 16 lanes, so 4 steps give an inclusive 16-lane prefix scan per row.
#define DPP_ADD(x, ctrl)                                                       \
    (x) += __int_as_float(__builtin_amdgcn_update_dpp(                         \
        0, __float_as_int(x), (ctrl), 0xf, 0xf, false))

// Fully-decoupled design: 1 ray = 1 wave = 1 block (64 threads), grid = N.
// NO LDS, NO barriers, NO separate epilogue. Per MFMA tile (16 samples):
// layer1 = 4x mfma_f32_16x16x32_f16 (dim-permuted W1^T, bias at k=6),
// layer2 = 2x; then the compositing is fused ONLINE: g=0 lanes hold
// {sigma,tex} of samples 16t+m in registers, compute fe, 4-step DPP row-scan
// for the in-tile prefix, readlane(15) row total -> running scalar S,
// p = exp(-(S+excl)) - exp(-(S+incl)), accumulate 5 ray-reductions in regs.
// g!=0 lanes compute harmless zeros (their o[] rows are zero). Final 4-step
// DPP row-scan reduces the accumulators; lane 15 writes the 5 ray outputs.
__global__ __launch_bounds__(64, 4)
void volrend_kernel(const float* __restrict__ ray_start,
                    const float* __restrict__ ray_dir,
                    const float* __restrict__ depth,
                    const float* __restrict__ dists,
                    const int*   __restrict__ vidx,
                    const float* __restrict__ vcol_tab,
                    const float* __restrict__ W1,
                    const float* __restrict__ b1,
                    const float* __restrict__ w_sigma,
                    const float* __restrict__ b_sigma,
                    const float* __restrict__ W_tex,
                    const float* __restrict__ b_tex,
                    float* __restrict__ out_colors,
                    float* __restrict__ out_depths,
                    float* __restrict__ out_missed,
                    float* __restrict__ out_probs) {
    const int lane = threadIdx.x;            // block == one wave
    const int ray  = __builtin_amdgcn_readfirstlane(blockIdx.x);
    const int m    = lane & 15;              // sample index inside MFMA tile
    const int g    = lane >> 4;              // K-slice lane group

    // --- per-ray uniforms (wave-uniform -> scalar loads) ---
    const float rs0 = ray_start[ray * 3 + 0];
    const float rs1 = ray_start[ray * 3 + 1];
    const float rs2 = ray_start[ray * 3 + 2];
    const float rd0 = ray_dir[ray * 3 + 0];
    const float rd1 = ray_dir[ray * 3 + 1];
    const float rd2 = ray_dir[ray * 3 + 2];
    const float bs  = b_sigma[0];
    const float bt0 = b_tex[0], bt1 = b_tex[1], bt2 = b_tex[2];

    // --- build fragments in-register (ray-independent; L2-hot broadcast) ---
    half8 a1[4];
    #pragma unroll
    for (int tt = 0; tt < 4; ++tt) {
        const int dim = 8 * (m >> 2) + (m & 3) + 4 * (tt & 1) + 32 * (tt >> 1);
        half8 a = h8zero();
        if (g == 0) {
            #pragma unroll
            for (int j = 0; j < 6; ++j) a[j] = (_Float16)W1[j * D_HID + dim];
            a[6] = (_Float16)b1[dim];
        }
        a1[tt] = a;
    }
    half8 a2a = h8zero(), a2b = h8zero();
    if (m < 4) {
        const int c = (m >= 1) ? (m - 1) : 0;
        #pragma unroll
        for (int j = 0; j < 8; ++j) {
            const int d = 8 * g + j;
            a2a[j] = (_Float16)((m == 0) ? w_sigma[d]      : W_tex[d * 3 + c]);
            a2b[j] = (_Float16)((m == 0) ? w_sigma[d + 32] : W_tex[(d + 32) * 3 + c]);
        }
    }

    f32x4 oinit = {0.f, 0.f, 0.f, 0.f};
    if (g == 0) { oinit[0] = bs; oinit[1] = bt0; oinit[2] = bt1; oinit[3] = bt2; }
    const f32x4 zero4 = {0.f, 0.f, 0.f, 0.f};

    const fp16x2 hc12 = __builtin_amdgcn_cvt_pkrtz(rd1, rd2);
    const fp16x2 hc3  = __builtin_amdgcn_cvt_pkrtz(1.0f, 0.0f);

    const size_t rayBase = (size_t)ray * K_SAMP;

    float S = 0.f;                            // running fe prefix (wave-uniform)
    float accP = 0.f, accD = 0.f, accC0 = 0.f, accC1 = 0.f, accC2 = 0.f;

    #pragma unroll 2
    for (int t = 0; t < 16; ++t) {
        const int  n   = 16 * t + m;          // this lane-column's sample
        const float dpt = depth[rayBase + n];
        const float fx = fmaf(rd0, dpt, rs0);
        const float fy = fmaf(rd1, dpt, rs1);
        const float fz = fmaf(rd2, dpt, rs2);
        H8P bb;
        bb.h2[0] = __builtin_amdgcn_cvt_pkrtz(fx, fy);
        bb.h2[1] = __builtin_amdgcn_cvt_pkrtz(fz, rd0);
        bb.h2[2] = hc12;
        bb.h2[3] = hc3;
        const f32x4 h0 = __builtin_amdgcn_mfma_f32_16x16x32_f16(a1[0], bb.h8, zero4, 0, 0, 0);
        const f32x4 h1 = __builtin_amdgcn_mfma_f32_16x16x32_f16(a1[1], bb.h8, zero4, 0, 0, 0);
        const f32x4 h2 = __builtin_amdgcn_mfma_f32_16x16x32_f16(a1[2], bb.h8, zero4, 0, 0, 0);
        const f32x4 h3 = __builtin_amdgcn_mfma_f32_16x16x32_f16(a1[3], bb.h8, zero4, 0, 0, 0);

        H8P p2a, p2b;
        p2a.h2[0] = __builtin_amdgcn_cvt_pkrtz(fmaxf(h0[0], 0.f), fmaxf(h0[1], 0.f));
        p2a.h2[1] = __builtin_amdgcn_cvt_pkrtz(fmaxf(h0[2], 0.f), fmaxf(h0[3], 0.f));
        p2a.h2[2] = __builtin_amdgcn_cvt_pkrtz(fmaxf(h1[0], 0.f), fmaxf(h1[1], 0.f));
        p2a.h2[3] = __builtin_amdgcn_cvt_pkrtz(fmaxf(h1[2], 0.f), fmaxf(h1[3], 0.f));
        p2b.h2[0] = __builtin_amdgcn_cvt_pkrtz(fmaxf(h2[0], 0.f), fmaxf(h2[1], 0.f));
        p2b.h2[1] = __builtin_amdgcn_cvt_pkrtz(fmaxf(h2[2], 0.f), fmaxf(h2[3], 0.f));
        p2b.h2[2] = __builtin_amdgcn_cvt_pkrtz(fmaxf(h3[0], 0.f), fmaxf(h3[1], 0.f));
        p2b.h2[3] = __builtin_amdgcn_cvt_pkrtz(fmaxf(h3[2], 0.f), fmaxf(h3[3], 0.f));

        f32x4 o = oinit;
        o = __builtin_amdgcn_mfma_f32_16x16x32_f16(a2a, p2a.h8, o, 0, 0, 0);
        o = __builtin_amdgcn_mfma_f32_16x16x32_f16(a2b, p2b.h8, o, 0, 0, 0);

        // --- fused online compositing (valid in g=0 lanes; zeros elsewhere) ---
        const float dstv = dists[rayBase + n];
        const int   viv  = vidx[rayBase + n];
        const bool  mk   = (viv != -1);
        const int   vb   = (mk ? viv : 0) * 3;
        const float vc0  = vcol_tab[vb + 0];
        const float vc1  = vcol_tab[vb + 1];
        const float vc2  = vcol_tab[vb + 2];

        const float fe = mk ? fmaxf(o[0], 0.f) * dstv * SCALER_FE : 0.f;
        float incl = fe;                       // 16-lane inclusive row scan
        DPP_ADD(incl, 0x111);
        DPP_ADD(incl, 0x112);
        DPP_ADD(incl, 0x114);
        DPP_ADD(incl, 0x118);
        const float rowtot =
            __int_as_float(__builtin_amdgcn_readlane(__float_as_int(incl), 15));
        const float eB = S + incl;             // prefix including this sample
        const float eA = eB - fe;              // exclusive prefix
        const float p  = __expf(-eA) - __expf(-eB);
        S += rowtot;

        if (g == 0) out_probs[rayBase + n] = p;

        const float tA = mk ? o[1] + vc0 : 0.f;
        const float tB = mk ? o[2] + vc1 : 0.f;
        const float tC = mk ? o[3] + vc2 : 0.f;
        accP += p;
        accD  = fmaf(dpt, p, accD);
        accC0 = fmaf(tA,  p, accC0);
        accC1 = fmaf(tB,  p, accC1);
        accC2 = fmaf(tC,  p, accC2);
    }

    // --- final 16-lane row reduction; lane 15 holds row-0 totals ---
    DPP_ADD(accP,  0x111); DPP_ADD(accP,  0x112); DPP_ADD(accP,  0x114); DPP_ADD(accP,  0x118);
    DPP_ADD(accD,  0x111); DPP_ADD(accD,  0x112); DPP_ADD(accD,  0x114); DPP_ADD(accD,  0x118);
    DPP_ADD(accC0, 0x111); DPP_ADD(accC0, 0x112); DPP_ADD(accC0, 0x114); DPP_ADD(accC0, 0x118);
    DPP_ADD(accC1, 0x111); DPP_ADD(accC1, 0x112); DPP_ADD(accC1, 0x114); DPP_ADD(accC1, 0x118);
    DPP_ADD(accC2, 0x111); DPP_ADD(accC2, 0x112); DPP_ADD(accC2, 0x114); DPP_ADD(accC2, 0x118);
    if (lane == 15) {
        out_colors[ray * 3 + 0] = accC0;
        out_colors[ray * 3 + 1] = accC1;
        out_colors[ray * 3 + 2] = accC2;
        out_depths[ray] = accD;
        out_missed[ray] = 1.0f - accP;
    }
}

extern "C" void kernel_launch(void* const* d_in, const int* in_sizes, int n_in,
                              void* d_out, int out_size, void* d_ws, size_t ws_size,
                              hipStream_t stream) {
    const float* ray_start  = (const float*)d_in[0];
    const float* ray_dir    = (const float*)d_in[1];
    const float* depth      = (const float*)d_in[2];
    const float* dists      = (const float*)d_in[3];
    const int*   vidx       = (const int*)d_in[4];
    const float* vcol       = (const float*)d_in[5];
    const float* W1         = (const float*)d_in[6];
    const float* b1         = (const float*)d_in[7];
    const float* w_sigma    = (const float*)d_in[8];
    const float* b_sigma    = (const float*)d_in[9];
    const float* W_tex      = (const float*)d_in[10];
    const float* b_tex      = (const float*)d_in[11];

    const int N = in_sizes[0] / 3;       // 4096 rays
    float* out        = (float*)d_out;
    float* out_colors = out;
    float* out_depths = out + (size_t)N * 3;
    float* out_missed = out + (size_t)N * 3 + N;
    float* out_probs  = out + (size_t)N * 3 + 2 * (size_t)N;

    volrend_kernel<<<N, 64, 0, stream>>>(
        ray_start, ray_dir, depth, dists, vidx, vcol,
        W1, b1, w_sigma, b_sigma, W_tex, b_tex,
        out_colors, out_depths, out_missed, out_probs);
}